// Round 1
// baseline (1225.770 us; speedup 1.0000x reference)
//
#include <hip/hip_runtime.h>
#include <hip/hip_bf16.h>

// Problem dims (fixed by setup_inputs):
//   N=64, C=192, T=64, V=25, H=6, d=32, B=N*V=1600
#define N_ 64
#define C_ 192
#define T_ 64
#define V_ 25
#define H_ 6
#define D_ 32
#define B_ 1600   // N_*V_

// ---------------------------------------------------------------------------
// Kernel 1: transpose x (N,C,T,V) -> xr (B=N*V, C, T)
// one block per (n,c): a 64x25 tile
// ---------------------------------------------------------------------------
__global__ __launch_bounds__(256) void k_transpose(const float* __restrict__ x,
                                                   float* __restrict__ xr) {
    int n = blockIdx.x / C_;
    int c = blockIdx.x % C_;
    const float* src = x + ((size_t)n * C_ + c) * (T_ * V_);  // (t,v) row-major
    __shared__ float tile[T_ * V_];
    for (int i = threadIdx.x; i < T_ * V_; i += 256) tile[i] = src[i];
    __syncthreads();
    // out: xr[(n*V+v)*C*T + c*T + t], coalesced in t
    for (int i = threadIdx.x; i < T_ * V_; i += 256) {
        int v = i / T_;
        int t = i % T_;
        xr[((size_t)(n * V_ + v) * C_ + c) * T_ + t] = tile[t * V_ + v];
    }
}

// ---------------------------------------------------------------------------
// Kernel 2: QKV GEMM  qkv[b] = w_qkv(576x192) @ xr[b](192x64) + b_qkv
// grid = B * 9 blocks; each block computes a 64x64 output tile
// ---------------------------------------------------------------------------
__global__ __launch_bounds__(256) void k_qkv_gemm(const float* __restrict__ W,
                                                  const float* __restrict__ bias,
                                                  const float* __restrict__ X,
                                                  float* __restrict__ Y) {
    int bid = blockIdx.x;
    int b  = bid / 9;
    int mo = bid % 9;                       // o0 = mo*64
    const float* Xb = X + (size_t)b * C_ * T_;
    float* Yb = Y + (size_t)b * (3 * C_) * T_;

    __shared__ float As[64][33];            // [m][k], padded
    __shared__ float Bs[32][64];            // [k][t]

    int tid = threadIdx.x;
    int tx = tid & 15;                      // t group
    int ty = tid >> 4;                      // m group
    float acc[4][4] = {};

    for (int k0 = 0; k0 < C_; k0 += 32) {
        for (int i = tid; i < 64 * 32; i += 256) {
            int m = i >> 5, kk = i & 31;
            As[m][kk] = W[(size_t)(mo * 64 + m) * C_ + k0 + kk];
        }
        for (int i = tid; i < 32 * 64; i += 256) {
            int kk = i >> 6, t = i & 63;
            Bs[kk][t] = Xb[(size_t)(k0 + kk) * T_ + t];
        }
        __syncthreads();
        for (int kk = 0; kk < 32; ++kk) {
            float a[4], bb[4];
#pragma unroll
            for (int i = 0; i < 4; ++i) a[i] = As[ty * 4 + i][kk];
#pragma unroll
            for (int j = 0; j < 4; ++j) bb[j] = Bs[kk][tx * 4 + j];
#pragma unroll
            for (int i = 0; i < 4; ++i)
#pragma unroll
                for (int j = 0; j < 4; ++j) acc[i][j] += a[i] * bb[j];
        }
        __syncthreads();
    }
#pragma unroll
    for (int i = 0; i < 4; ++i) {
        int o = mo * 64 + ty * 4 + i;
        float bv = bias[o];
#pragma unroll
        for (int j = 0; j < 4; ++j)
            Yb[(size_t)o * T_ + tx * 4 + j] = acc[i][j] + bv;
    }
}

// ---------------------------------------------------------------------------
// Kernel 3: fused attention per (b,h).
//   logits[t][s] = sum_d q[d][t]*k[d][s] + sum_d q[d][t]*rel[s-t+63][d]
//   softmax over s, attn[t][dd] = sum_s w[t][s] v[dd][s]
//   write with the reference's reshape-scramble:
//     attnR[b, h*32+q, tout] = attn[2*(tout%32)+(j>=32)][j%32], j = 2q + tout/32
// ---------------------------------------------------------------------------
__global__ __launch_bounds__(256) void k_attn(const float* __restrict__ qkv,
                                              const float* __restrict__ rel_emb,
                                              float* __restrict__ attnR) {
    int bid = blockIdx.x;                   // B*H
    int b = bid / H_;
    int h = bid % H_;
    const float* base = qkv + (size_t)b * (3 * C_) * T_;

    __shared__ float qs[D_][T_];
    __shared__ float ks[D_][T_];
    __shared__ float vs[D_][T_];
    __shared__ float rk[2 * T_ - 1][D_];    // 127 x 32
    __shared__ float wt[T_][T_];
    __shared__ float ao[T_][D_];

    int tid = threadIdx.x;
    const float* qsrc = base + (size_t)(h * D_) * T_;
    const float* ksrc = base + (size_t)(C_ + h * D_) * T_;
    const float* vsrc = base + (size_t)(2 * C_ + h * D_) * T_;
    for (int i = tid; i < D_ * T_; i += 256) {
        ((float*)qs)[i] = qsrc[i];
        ((float*)ks)[i] = ksrc[i];
        ((float*)vs)[i] = vsrc[i];
    }
    for (int i = tid; i < (2 * T_ - 1) * D_; i += 256) ((float*)rk)[i] = rel_emb[i];
    __syncthreads();

    // logits + softmax: thread owns row t = tid>>2, 16 s-values (quad = tid&3)
    int t = tid >> 2;
    int quad = tid & 3;
    float vals[16];
    float mx = -INFINITY;
#pragma unroll
    for (int si = 0; si < 16; ++si) {
        int s = quad * 16 + si;
        int m = s - t + (T_ - 1);
        float acc = 0.f;
#pragma unroll
        for (int dd = 0; dd < D_; ++dd) {
            float qv = qs[dd][t];
            acc += qv * ks[dd][s];
            acc += qv * rk[m][dd];
        }
        vals[si] = acc;
        mx = fmaxf(mx, acc);
    }
    mx = fmaxf(mx, __shfl_xor(mx, 1));
    mx = fmaxf(mx, __shfl_xor(mx, 2));
    float sum = 0.f;
#pragma unroll
    for (int si = 0; si < 16; ++si) {
        vals[si] = expf(vals[si] - mx);
        sum += vals[si];
    }
    sum += __shfl_xor(sum, 1);
    sum += __shfl_xor(sum, 2);
    float inv = 1.0f / sum;
#pragma unroll
    for (int si = 0; si < 16; ++si) wt[t][quad * 16 + si] = vals[si] * inv;
    __syncthreads();

    // PV: thread computes (t = tid>>2, 8 dd values)
    {
        int tt = tid >> 2;
        int g = tid & 3;
        float acc8[8] = {};
        for (int s = 0; s < T_; ++s) {
            float w = wt[tt][s];
#pragma unroll
            for (int u = 0; u < 8; ++u) acc8[u] += w * vs[g * 8 + u][s];
        }
#pragma unroll
        for (int u = 0; u < 8; ++u) ao[tt][g * 8 + u] = acc8[u];
    }
    __syncthreads();

    // scrambled write (reference reshape(B,H,d,1,T).transpose(0,1,3,4,2))
    float* dst = attnR + ((size_t)b * C_ + h * D_) * T_;
    for (int i = tid; i < D_ * T_; i += 256) {
        int qr = i >> 6;                    // c%32
        int tout = i & 63;
        int ii = tout & 31;
        int j = 2 * qr + (tout >> 5);
        int tA = 2 * ii + (j >> 5);
        int dA = j & 31;
        dst[i] = ao[tA][dA];
    }
}

// ---------------------------------------------------------------------------
// Kernel 4: output GEMM  out[b] = w_out(192x192) @ attnR[b](192x64) + b_out
// writes straight into final (N, C, T, V) layout
// grid = B * 3
// ---------------------------------------------------------------------------
__global__ __launch_bounds__(256) void k_out_gemm(const float* __restrict__ W,
                                                  const float* __restrict__ bias,
                                                  const float* __restrict__ X,
                                                  float* __restrict__ out) {
    int bid = blockIdx.x;
    int b  = bid / 3;
    int mo = bid % 3;
    const float* Xb = X + (size_t)b * C_ * T_;

    __shared__ float As[64][33];
    __shared__ float Bs[32][64];

    int tid = threadIdx.x;
    int tx = tid & 15;
    int ty = tid >> 4;
    float acc[4][4] = {};

    for (int k0 = 0; k0 < C_; k0 += 32) {
        for (int i = tid; i < 64 * 32; i += 256) {
            int m = i >> 5, kk = i & 31;
            As[m][kk] = W[(size_t)(mo * 64 + m) * C_ + k0 + kk];
        }
        for (int i = tid; i < 32 * 64; i += 256) {
            int kk = i >> 6, t = i & 63;
            Bs[kk][t] = Xb[(size_t)(k0 + kk) * T_ + t];
        }
        __syncthreads();
        for (int kk = 0; kk < 32; ++kk) {
            float a[4], bb[4];
#pragma unroll
            for (int i = 0; i < 4; ++i) a[i] = As[ty * 4 + i][kk];
#pragma unroll
            for (int j = 0; j < 4; ++j) bb[j] = Bs[kk][tx * 4 + j];
#pragma unroll
            for (int i = 0; i < 4; ++i)
#pragma unroll
                for (int j = 0; j < 4; ++j) acc[i][j] += a[i] * bb[j];
        }
        __syncthreads();
    }

    int n = b / V_;
    int v = b % V_;
#pragma unroll
    for (int i = 0; i < 4; ++i) {
        int o = mo * 64 + ty * 4 + i;
        float bv = bias[o];
#pragma unroll
        for (int j = 0; j < 4; ++j) {
            int tcol = tx * 4 + j;
            out[((size_t)n * C_ + o) * (T_ * V_) + (size_t)tcol * V_ + v] =
                acc[i][j] + bv;
        }
    }
}

// ---------------------------------------------------------------------------
extern "C" void kernel_launch(void* const* d_in, const int* in_sizes, int n_in,
                              void* d_out, int out_size, void* d_ws, size_t ws_size,
                              hipStream_t stream) {
    const float* x       = (const float*)d_in[0];
    const float* w_qkv   = (const float*)d_in[1];
    const float* b_qkv   = (const float*)d_in[2];
    const float* w_out   = (const float*)d_in[3];
    const float* b_out   = (const float*)d_in[4];
    const float* rel_emb = (const float*)d_in[5];
    float* out = (float*)d_out;

    // workspace layout (floats):
    //   xr    : B*C*T = 19,660,800   (later reused as attnR)
    //   qkv   : B*3C*T = 58,982,400
    float* xr    = (float*)d_ws;
    float* qkv   = xr + (size_t)B_ * C_ * T_;
    float* attnR = xr;  // reuse: xr dead after QKV GEMM

    k_transpose<<<N_ * C_, 256, 0, stream>>>(x, xr);
    k_qkv_gemm<<<B_ * 9, 256, 0, stream>>>(w_qkv, b_qkv, xr, qkv);
    k_attn<<<B_ * H_, 256, 0, stream>>>(qkv, rel_emb, attnR);
    k_out_gemm<<<B_ * 3, 256, 0, stream>>>(w_out, b_out, attnR, out);
}